// Round 1
// baseline (116.254 us; speedup 1.0000x reference)
//
#include <hip/hip_runtime.h>

// SparseConv3D: out[N,64] = sp[N,64] @ Wc + bias + scatter-add over 26 offset taps.
// bf16 MFMA 16x16x32, fp32 accumulate. Two kernels (center init, then atomic scatter).

typedef __bf16 bf16x8 __attribute__((ext_vector_type(8)));
typedef float f32x4 __attribute__((ext_vector_type(4)));

#define LDSP 72  // padded LDS row stride in bf16 elems: 144B rows -> frag b128 reads ~2-way (free)

__device__ __forceinline__ unsigned short f2bf(float f) {
    union { float f; unsigned int u; } v; v.f = f;
    unsigned int u = v.u;
    return (unsigned short)((u + 0x7FFFu + ((u >> 16) & 1u)) >> 16);  // RNE
}

__device__ __forceinline__ ushort4 cvt4(float4 v) {
    ushort4 b;
    b.x = f2bf(v.x); b.y = f2bf(v.y); b.z = f2bf(v.z); b.w = f2bf(v.w);
    return b;
}

// ---- center tap: out = sp @ W[13] + bias (plain store, initializes d_out) ----
__global__ __launch_bounds__(256) void sp3d_center(
    const float* __restrict__ sp, const float* __restrict__ w,
    const float* __restrict__ bias, float* __restrict__ out, int n_rows)
{
    __shared__ unsigned short Alds[64 * LDSP];
    __shared__ unsigned short Wlds[64 * LDSP];
    const int t = threadIdx.x;
    const int row0 = blockIdx.x * 64;

    // stage center weight tile: Wlds[n][k] = w[n*1728 + 13*64 + k], f32->bf16
    for (int i = 0; i < 4; ++i) {
        int f4 = t + 256 * i;                 // float4 id, coalesced
        int n = f4 >> 4, k = (f4 & 15) << 2;
        float4 v = *(const float4*)&w[n * 1728 + 832 + k];
        *(ushort4*)&Wlds[n * LDSP + k] = cvt4(v);
    }
    // stage sp tile (64 rows), f32->bf16
    {
        int r = t >> 2, q = t & 3;
        long rowg = row0 + r;
        if (rowg >= n_rows) rowg = n_rows - 1;  // clamp loads; stores masked below
        for (int i = 0; i < 4; ++i) {
            int col = q * 4 + i * 16;
            float4 v = *(const float4*)&sp[rowg * 64 + col];
            *(ushort4*)&Alds[r * LDSP + col] = cvt4(v);
        }
    }
    __syncthreads();

    const int wid = t >> 6, lane = t & 63, ml = lane & 15, quad = lane >> 4;
    // A frag: A[m=lane&15][k=quad*8+j]
    const bf16x8 a0 = *(const bf16x8*)&Alds[(wid * 16 + ml) * LDSP + quad * 8];
    const bf16x8 a1 = *(const bf16x8*)&Alds[(wid * 16 + ml) * LDSP + 32 + quad * 8];
    f32x4 acc[4];
    #pragma unroll
    for (int nt = 0; nt < 4; ++nt) {
        // B frag: B[k=quad*8+j][n=lane&15] == Wlds row (cout-major) contiguous read
        bf16x8 b0 = *(const bf16x8*)&Wlds[(nt * 16 + ml) * LDSP + quad * 8];
        bf16x8 b1 = *(const bf16x8*)&Wlds[(nt * 16 + ml) * LDSP + 32 + quad * 8];
        acc[nt] = f32x4{0.f, 0.f, 0.f, 0.f};
        acc[nt] = __builtin_amdgcn_mfma_f32_16x16x32_bf16(a0, b0, acc[nt], 0, 0, 0);
        acc[nt] = __builtin_amdgcn_mfma_f32_16x16x32_bf16(a1, b1, acc[nt], 0, 0, 0);
    }
    // C/D layout: col=lane&15, row=quad*4+reg
    #pragma unroll
    for (int nt = 0; nt < 4; ++nt) {
        int col = nt * 16 + ml;
        float bv = bias[col];
        #pragma unroll
        for (int rg = 0; rg < 4; ++rg) {
            int row = row0 + wid * 16 + quad * 4 + rg;
            if (row < n_rows) out[row * 64 + col] = acc[nt][rg] + bv;
        }
    }
}

// ---- neighbor taps: gather rows, small GEMM per offset, atomicAdd scatter ----
__global__ __launch_bounds__(256) void sp3d_scatter(
    const float* __restrict__ sp, const float* __restrict__ w,
    const int* __restrict__ nei, const int* __restrict__ sizes,
    float* __restrict__ out, int P)
{
    __shared__ unsigned short Alds[64 * LDSP];
    __shared__ unsigned short Wlds[64 * LDSP];
    __shared__ int sO[64];
    __shared__ int sI[64];

    const int o = blockIdx.y;
    const int size_o = sizes[o];
    const int chunk = blockIdx.x * 64;
    if (chunk >= size_o) return;  // block-uniform
    const int t = threadIdx.x;
    const int tap = o + (o >= 13 ? 1 : 0);  // offsets enumeration skips center (idx 13)

    if (t < 64) {
        int p = chunk + t;
        if (p < size_o) {
            int2 pr = *(const int2*)&nei[(o * P + p) * 2];
            sO[t] = pr.x; sI[t] = pr.y;
        } else { sO[t] = -1; sI[t] = 0; }
    }
    // stage this offset's weight tile
    for (int i = 0; i < 4; ++i) {
        int f4 = t + 256 * i;
        int n = f4 >> 4, k = (f4 & 15) << 2;
        float4 v = *(const float4*)&w[n * 1728 + tap * 64 + k];
        *(ushort4*)&Wlds[n * LDSP + k] = cvt4(v);
    }
    __syncthreads();

    // gather 64 input rows via sI
    {
        int r = t >> 2, q = t & 3;
        long rowg = sI[r];
        for (int i = 0; i < 4; ++i) {
            int col = q * 4 + i * 16;
            float4 v = *(const float4*)&sp[rowg * 64 + col];
            *(ushort4*)&Alds[r * LDSP + col] = cvt4(v);
        }
    }
    __syncthreads();

    const int wid = t >> 6, lane = t & 63, ml = lane & 15, quad = lane >> 4;
    const bf16x8 a0 = *(const bf16x8*)&Alds[(wid * 16 + ml) * LDSP + quad * 8];
    const bf16x8 a1 = *(const bf16x8*)&Alds[(wid * 16 + ml) * LDSP + 32 + quad * 8];
    f32x4 acc[4];
    #pragma unroll
    for (int nt = 0; nt < 4; ++nt) {
        bf16x8 b0 = *(const bf16x8*)&Wlds[(nt * 16 + ml) * LDSP + quad * 8];
        bf16x8 b1 = *(const bf16x8*)&Wlds[(nt * 16 + ml) * LDSP + 32 + quad * 8];
        acc[nt] = f32x4{0.f, 0.f, 0.f, 0.f};
        acc[nt] = __builtin_amdgcn_mfma_f32_16x16x32_bf16(a0, b0, acc[nt], 0, 0, 0);
        acc[nt] = __builtin_amdgcn_mfma_f32_16x16x32_bf16(a1, b1, acc[nt], 0, 0, 0);
    }
    #pragma unroll
    for (int nt = 0; nt < 4; ++nt) {
        int col = nt * 16 + ml;
        #pragma unroll
        for (int rg = 0; rg < 4; ++rg) {
            int rowl = wid * 16 + quad * 4 + rg;
            int go = sO[rowl];
            if (go >= 0) atomicAdd(&out[go * 64 + col], acc[nt][rg]);
        }
    }
}

extern "C" void kernel_launch(void* const* d_in, const int* in_sizes, int n_in,
                              void* d_out, int out_size, void* d_ws, size_t ws_size,
                              hipStream_t stream) {
    const float* sp    = (const float*)d_in[0];
    const float* w     = (const float*)d_in[1];
    const float* bias  = (const float*)d_in[2];
    const int*   nei   = (const int*)d_in[3];
    const int*   sizes = (const int*)d_in[4];
    float* out = (float*)d_out;

    const int N = in_sizes[0] / 64;
    const int P = in_sizes[3] / (26 * 2);

    dim3 g1((N + 63) / 64);
    sp3d_center<<<g1, 256, 0, stream>>>(sp, w, bias, out, N);

    dim3 g2((P + 63) / 64, 26);
    sp3d_scatter<<<g2, 256, 0, stream>>>(sp, w, nei, sizes, out, P);
}